// Round 19
// baseline (229.774 us; speedup 1.0000x reference)
//
#include <hip/hip_runtime.h>
#include <hip/hip_bf16.h>
#include <stdint.h>

typedef short short8 __attribute__((ext_vector_type(8)));
typedef float f32x4 __attribute__((ext_vector_type(4)));

#define NB    32
#define NC    512
#define NHD   8
#define HDD   64
#define N7    49
#define RES   56
#define P56   3136
#define NTOK  1568     // 32*49
#define NTOKP 1664     // padded to 13*128 for unguarded staging
#define NBIG  100352   // 32*3136
#define KDIM  512
#define KLOC  576      // 64ci * 9taps

// async global->LDS, 16B per lane; LDS dest is wave-uniform base + lane*16
__device__ __forceinline__ void gload_lds16(const __hip_bfloat16* g, __hip_bfloat16* l) {
  __builtin_amdgcn_global_load_lds(
      (const __attribute__((address_space(1))) void*)g,
      (__attribute__((address_space(3))) void*)l, 16, 0, 0);
}

// ---------------------------------------------------------------- fused: depthwise 3x3 stride-8 + BN0 (blocks 0..4095)
//                                                                   + fp32->bf16 weight convert (blocks 4096..4751)
__global__ __launch_bounds__(256) void k_stride_cvt(
    const float* __restrict__ x, const float* __restrict__ dw,
    const float* __restrict__ s0, const float* __restrict__ b0,
    __hip_bfloat16* __restrict__ xs,
    const float* __restrict__ c0, const float* __restrict__ c1,
    const float* __restrict__ c2, const float* __restrict__ c3,
    const float* __restrict__ c4,
    __hip_bfloat16* __restrict__ d0, __hip_bfloat16* __restrict__ d1,
    __hip_bfloat16* __restrict__ d2, __hip_bfloat16* __restrict__ d3,
    __hip_bfloat16* __restrict__ d4) {
  const int bid = blockIdx.x, t = threadIdx.x;
  if (bid >= 4096) {
    const long base = (long)(bid - 4096) * 2048;
#pragma unroll
    for (int j = 0; j < 8; ++j) {
      long i = base + t + j * 256;
      const float* s; __hip_bfloat16* d; long off;
      if (i >= 1048576)      { s = c4; d = d4; off = i - 1048576; }
      else if (i >= 786432)  { s = c3; d = d3; off = i - 786432; }
      else if (i >= 524288)  { s = c2; d = d2; off = i - 524288; }
      else if (i >= 262144)  { s = c1; d = d1; off = i - 262144; }
      else                   { s = c0; d = d0; off = i; }
      d[off] = __float2bfloat16(s[off]);
    }
    return;
  }
  const int b = bid >> 7, cig = bid & 127;
  const int sub = t >> 6, lane = t & 63;
  const int ci = cig * 4 + sub;
  __shared__ float rows[4][21][56];
  const float* xp = x + ((size_t)(b * NC + ci)) * RES * RES;
  for (int r = lane; r < 21 * 56; r += 64) {
    int rr = r / 56, cc = r - rr * 56;
    int oh = rr / 3, kh = rr - oh * 3;
    int ih = oh * 8 + kh - 1;
    rows[sub][rr][cc] = (ih >= 0) ? xp[ih * 56 + cc] : 0.f;
  }
  float w[9];
#pragma unroll
  for (int j = 0; j < 9; ++j) w[j] = dw[ci * 9 + j];
  const float sc = s0[ci], bi = b0[ci];
  __syncthreads();
  if (lane < 49) {
    const int oh = lane / 7, ow = lane - oh * 7;
    float acc = 0.f;
#pragma unroll
    for (int kh = 0; kh < 3; ++kh)
#pragma unroll
      for (int kw = 0; kw < 3; ++kw) {
        int col = ow * 8 + kw - 1;
        float v = (col >= 0) ? rows[sub][oh * 3 + kh][col] : 0.f;
        acc += v * w[kh * 3 + kw];
      }
    xs[(size_t)(b * 49 + lane) * NC + ci] = __float2bfloat16(acc * sc + bi);
  }
}

// ---------------------------------------------------------------- BIG GEMM: 256x256, BK=32, ring-2, 2 resident blocks/CU,
// counted vmcnt(4), verified conflict-free swizzle, LDS-transpose epilogue
// with NON-TEMPORAL dwordx4 stores (confirmed -17us, R17).
__global__ __launch_bounds__(512) void k_gemm_big(
    const __hip_bfloat16* __restrict__ A,    // [512][512] bf16
    const __hip_bfloat16* __restrict__ Bm,   // [100352][512] bf16
    const float* __restrict__ scale, const float* __restrict__ bias,
    float* __restrict__ out) {
  __shared__ __align__(16) __hip_bfloat16 lsA[2][256 * 32];   // 32 KB
  __shared__ __align__(16) __hip_bfloat16 lsB[2][256 * 32];   // 32 KB
  const int t = threadIdx.x;
  const int cpx = gridDim.x >> 3;
  const int nid = (blockIdx.x & 7) * cpx + (blockIdx.x >> 3);
  const int m0 = (nid & 1) * 256, n0 = (nid >> 1) * 256;

  const int lane = t & 63, wid = t >> 6;
  const int wm = (wid >> 2) * 128, wn = (wid & 3) * 64;   // 2M x 4N waves
  const int fr = lane & 15, fq = lane >> 4;
  const int rslot = (fq ^ ((fr >> 1) & 3)) * 8;           // verified conflict-free

  const int srow = t >> 2;                                 // 0..127
  const int scol = ((t & 3) ^ ((t >> 3) & 3)) * 8;         // stage-side inverse
  const __hip_bfloat16* Ab = A  + (size_t)(m0 + srow) * KDIM + scol;
  const __hip_bfloat16* Bb = Bm + (size_t)(n0 + srow) * KDIM + scol;

  const f32x4 fz = {0.f, 0.f, 0.f, 0.f};
  f32x4 acc[8][4];
#pragma unroll
  for (int i = 0; i < 8; ++i)
#pragma unroll
    for (int j = 0; j < 4; ++j) acc[i][j] = fz;

#define STA(tile, call) gload_lds16(Ab + (tile) * 32 + (size_t)(call) * 128 * KDIM, \
                                    lsA[(tile) & 1] + (call) * 4096 + wid * 512)
#define STB(tile, call) gload_lds16(Bb + (tile) * 32 + (size_t)(call) * 128 * KDIM, \
                                    lsB[(tile) & 1] + (call) * 4096 + wid * 512)

  STA(0, 0); STA(0, 1); STB(0, 0); STB(0, 1);
  STA(1, 0); STA(1, 1); STB(1, 0); STB(1, 1);

#pragma unroll 1
  for (int tt = 0; tt < 16; ++tt) {
    if (tt < 15) asm volatile("s_waitcnt vmcnt(4)" ::: "memory");
    else         asm volatile("s_waitcnt vmcnt(0)" ::: "memory");
    __builtin_amdgcn_sched_barrier(0);
    __builtin_amdgcn_s_barrier();          // buf[tt&1] = tile tt, visible to all
    __builtin_amdgcn_sched_barrier(0);

    const __hip_bfloat16* lA = lsA[tt & 1];
    const __hip_bfloat16* lB = lsB[tt & 1];
    short8 af[4], ag[4], bf[4];
#pragma unroll
    for (int i = 0; i < 4; ++i)
      af[i] = *(const short8*)(lA + (wm + i * 16 + fr) * 32 + rslot);
#pragma unroll
    for (int i = 0; i < 4; ++i)
      ag[i] = *(const short8*)(lA + (wm + 64 + i * 16 + fr) * 32 + rslot);
#pragma unroll
    for (int j = 0; j < 4; ++j)
      bf[j] = *(const short8*)(lB + (wn + j * 16 + fr) * 32 + rslot);
    __builtin_amdgcn_s_setprio(1);
#pragma unroll
    for (int i = 0; i < 4; ++i)
#pragma unroll
      for (int j = 0; j < 4; ++j)
        acc[i][j] = __builtin_amdgcn_mfma_f32_16x16x32_bf16(af[i], bf[j], acc[i][j], 0, 0, 0);
#pragma unroll
    for (int i = 0; i < 4; ++i)
#pragma unroll
      for (int j = 0; j < 4; ++j)
        acc[4 + i][j] = __builtin_amdgcn_mfma_f32_16x16x32_bf16(ag[i], bf[j], acc[4 + i][j], 0, 0, 0);
    __builtin_amdgcn_s_setprio(0);

    __builtin_amdgcn_sched_barrier(0);
    __builtin_amdgcn_s_barrier();          // all reads of buf[tt&1] complete
    __builtin_amdgcn_sched_barrier(0);
    if (tt < 14) { STA(tt + 2, 0); STA(tt + 2, 1); STB(tt + 2, 0); STB(tt + 2, 1); }
  }
#undef STA
#undef STB

  // ---- LDS-transpose epilogue, non-temporal dwordx4 stores.
  float* scr = (float*)&lsA[0][0] + (size_t)wid * 1100;   // 16*68=1088 used
  const int gnb = n0 + wn;                 // multiple of 64; never crosses P56
  const int outer = gnb / P56;
  const int iib = gnb - outer * P56;
  const int erow = lane >> 4;              // 0..3
  const int ecol = (lane & 15) * 4;        // 0..60
#pragma unroll
  for (int mi = 0; mi < 8; ++mi) {
    const int cob = m0 + wm + mi * 16;
#pragma unroll
    for (int ni = 0; ni < 4; ++ni) {
#pragma unroll
      for (int r = 0; r < 4; ++r) {
        const int co = cob + fq * 4 + r;
        scr[(fq * 4 + r) * 68 + ni * 16 + fr] = acc[mi][ni][r] * scale[co] + bias[co];
      }
    }
#pragma unroll
    for (int p = 0; p < 4; ++p) {
      const int row = p * 4 + erow;        // 0..15
      f32x4 v = *(const f32x4*)(scr + row * 68 + ecol);
      __builtin_nontemporal_store(
          v, (f32x4*)(&out[((size_t)outer * NC + cob + row) * P56 + iib + ecol]));
    }
  }
}

// ---------------------------------------------------------------- fused QKV GEMM (ring-2, unchanged)
__global__ __launch_bounds__(256) void k_gemm_qkv(
    const __hip_bfloat16* __restrict__ wqb, const __hip_bfloat16* __restrict__ wkb,
    const __hip_bfloat16* __restrict__ wvb, const __hip_bfloat16* __restrict__ xs,
    const float* __restrict__ sq, const float* __restrict__ bq,
    const float* __restrict__ sk, const float* __restrict__ bk,
    const float* __restrict__ sv, const float* __restrict__ bv,
    float* __restrict__ qb, float* __restrict__ kb, float* __restrict__ vb) {
  __shared__ __align__(16) __hip_bfloat16 lsA[2][128 * 32];
  __shared__ __align__(16) __hip_bfloat16 lsB[2][128 * 32];
  const int t = threadIdx.x;
  const int nwg = gridDim.x;
  const int orig = blockIdx.x;
  const int q = nwg >> 3, r = nwg & 7;
  const int xcd = orig & 7, pos = orig >> 3;
  const int nid = (xcd < r ? xcd * (q + 1) : r * (q + 1) + (xcd - r) * q) + pos;
  const int mt = nid % 12, nt = nid / 12;
  const int n0 = nt * 128, m0 = (mt & 3) * 128, sel = mt >> 2;

  const __hip_bfloat16* A = (sel == 0 ? wqb : sel == 1 ? wkb : wvb);
  const float* scale = (sel == 0 ? sq : sel == 1 ? sk : sv);
  const float* bias  = (sel == 0 ? bq : sel == 1 ? bk : bv);
  float* out = (sel == 0 ? qb : sel == 1 ? kb : vb);

  const int lane = t & 63, wid = t >> 6;
  const int wm = (wid >> 1) * 64, wn = (wid & 1) * 64;
  const int fr = lane & 15, fq = lane >> 4;
  const int rslot = (fq ^ ((fr >> 1) & 3)) * 8;
  const int srow = t >> 2;
  const int scol = ((t & 3) ^ ((t >> 3) & 3)) * 8;
  const __hip_bfloat16* Ab = A  + (size_t)(m0 + srow) * KDIM + scol;
  const __hip_bfloat16* Bb = xs + (size_t)(n0 + srow) * KDIM + scol;

  const f32x4 fz = {0.f, 0.f, 0.f, 0.f};
  f32x4 acc[4][4];
#pragma unroll
  for (int i = 0; i < 4; ++i)
#pragma unroll
    for (int j = 0; j < 4; ++j) acc[i][j] = fz;

#define STG_QKV(tile)                                                   \
  do {                                                                  \
    const int kof = (tile) * 32; const int bb = (tile) & 1;             \
    gload_lds16(Ab + kof,                       lsA[bb] + wid * 512);   \
    gload_lds16(Ab + kof + (size_t)64 * KDIM,   lsA[bb] + 2048 + wid * 512); \
    gload_lds16(Bb + kof,                       lsB[bb] + wid * 512);   \
    gload_lds16(Bb + kof + (size_t)64 * KDIM,   lsB[bb] + 2048 + wid * 512); \
  } while (0)

  STG_QKV(0);
  STG_QKV(1);
#pragma unroll 1
  for (int it = 0; it < 16; ++it) {
    if (it < 15) asm volatile("s_waitcnt vmcnt(4)" ::: "memory");
    else         asm volatile("s_waitcnt vmcnt(0)" ::: "memory");
    __builtin_amdgcn_sched_barrier(0);
    __builtin_amdgcn_s_barrier();
    __builtin_amdgcn_sched_barrier(0);
    const __hip_bfloat16* lA = lsA[it & 1];
    const __hip_bfloat16* lB = lsB[it & 1];
    short8 af[4], bf[4];
#pragma unroll
    for (int mi = 0; mi < 4; ++mi)
      af[mi] = *(const short8*)(lA + (wm + mi * 16 + fr) * 32 + rslot);
#pragma unroll
    for (int ni = 0; ni < 4; ++ni)
      bf[ni] = *(const short8*)(lB + (wn + ni * 16 + fr) * 32 + rslot);
#pragma unroll
    for (int mi = 0; mi < 4; ++mi)
#pragma unroll
      for (int ni = 0; ni < 4; ++ni)
        acc[mi][ni] = __builtin_amdgcn_mfma_f32_16x16x32_bf16(af[mi], bf[ni], acc[mi][ni], 0, 0, 0);
    __builtin_amdgcn_sched_barrier(0);
    __builtin_amdgcn_s_barrier();
    __builtin_amdgcn_sched_barrier(0);
    if (it < 14) STG_QKV(it + 2);
  }
#undef STG_QKV

#pragma unroll
  for (int mi = 0; mi < 4; ++mi) {
#pragma unroll
    for (int ni = 0; ni < 4; ++ni) {
      const int gn = n0 + wn + ni * 16 + fr;
      if (gn >= NTOK) continue;
      const int b = gn / 49, ii = gn - b * 49;
#pragma unroll
      for (int r = 0; r < 4; ++r) {
        const int co = m0 + wm + mi * 16 + fq * 4 + r;
        out[((size_t)b * NC + co) * 49 + ii] = acc[mi][ni][r] * scale[co] + bias[co];
      }
    }
  }
}

// ---------------------------------------------------------------- MID1: attn1 (blocks 0..255) || im2col (blocks 256..511)
__global__ __launch_bounds__(256) void k_mid1(
    const float* __restrict__ qb, const float* __restrict__ kb,
    const float* __restrict__ lsc, const float* __restrict__ ab, const int* __restrict__ bidx,
    float* __restrict__ Sbuf,
    const float* __restrict__ vb, __hip_bfloat16* __restrict__ bloc) {
  __shared__ __align__(16) char smem[25792];
  const int bid = blockIdx.x, t = threadIdx.x;
  if (bid < 256) {
    const int h = bid & 7, b = bid >> 3;
    float* qt  = (float*)smem;
    float* kt  = qt + 3136;
    float* nq  = kt + 3136;
    float* abl = nq + 49;
    const float* qs = qb + ((size_t)b * NC + h * 64) * 49;
    const float* ks = kb + ((size_t)b * NC + h * 64) * 49;
    for (int i = t; i < 64 * 49; i += 256) { qt[i] = qs[i]; kt[i] = ks[i]; }
    if (t < 49) abl[t] = ab[h * 49 + t];
    __syncthreads();
    if (t < 49) {
      float s = 0.f;
      for (int d = 0; d < 64; ++d) { float v = qt[d * 49 + t]; s += v * v; }
      nq[t] = fmaxf(sqrtf(s), 1e-12f);
    } else if (t >= 64 && t < 128) {
      const int d = t - 64;
      float s = 0.f;
      for (int m = 0; m < 49; ++m) { float v = kt[d * 49 + m]; s += v * v; }
      const float inv = 1.f / fmaxf(sqrtf(s), 1e-12f);
      for (int m = 0; m < 49; ++m) kt[d * 49 + m] *= inv;
    }
    __syncthreads();
    const float ls = expf(fminf(lsc[h], logf(100.f)));
    for (int idx = t; idx < 49 * 49; idx += 256) {
      const int n = idx / 49, m = idx - n * 49;
      float acc = 0.f;
      for (int d = 0; d < 64; ++d) acc += qt[d * 49 + n] * kt[d * 49 + m];
      Sbuf[(((size_t)b * NHD + h) * 49 + n) * 49 + m] = acc / nq[n] * ls + abl[bidx[idx]];
    }
  } else {
    const int i2 = bid - 256;
    const int g = i2 & 7, b = i2 >> 3;
    __hip_bfloat16* pad = (__hip_bfloat16*)smem;   // [64][81]
    for (int i = t; i < 64 * 81; i += 256) pad[i] = __float2bfloat16(0.f);
    __syncthreads();
    const float* src = vb + ((size_t)b * NC + g * 64) * 49;
    for (int i = t; i < 64 * 49; i += 256) {
      const int ci = i / 49, n = i - ci * 49;
      const int oh = n / 7, ow = n - oh * 7;
      pad[ci * 81 + (oh + 1) * 9 + (ow + 1)] = __float2bfloat16(src[i]);
    }
    __syncthreads();
    __hip_bfloat16* dst = bloc + ((size_t)g * NTOKP + (size_t)b * 49) * KLOC;
    for (int i8 = t; i8 < 49 * KLOC / 8; i8 += 256) {
      const int i = i8 * 8;
      const int n = i / KLOC, k0 = i - n * KLOC;
      const int oh = n / 7, ow = n - oh * 7;
      short8 pk;
#pragma unroll
      for (int j = 0; j < 8; ++j) {
        const int k = k0 + j;
        const int ci = k / 9, tap = k - ci * 9;
        const int kh = tap / 3, kw = tap - kh * 3;
        pk[j] = (short)__bfloat16_as_ushort(pad[ci * 81 + (oh + kh) * 9 + (ow + kw)]);
      }
      *(short8*)(dst + (size_t)n * KLOC + k0) = pk;
    }
  }
}

// ---------------------------------------------------------------- MID2: attn2-noVloc (blocks 0..1567) || vloc GEMM (1568..1671)
__global__ __launch_bounds__(256) void k_mid2(
    const float* __restrict__ Sbuf, const float* __restrict__ th1, const float* __restrict__ th2,
    const float* __restrict__ vb, float* __restrict__ y7,
    const __hip_bfloat16* __restrict__ lwb, const __hip_bfloat16* __restrict__ bloc,
    const float* __restrict__ lbias, const float* __restrict__ sl,
    const float* __restrict__ bl, float* __restrict__ vloc) {
  __shared__ __align__(16) char smem[24576];
  const int bid = blockIdx.x, t = threadIdx.x;
  if (bid < 1568) {
    const int n = bid % 49, b = bid / 49;
    float* sS = (float*)smem;
    float* sP = sS + 392;
    float* sQ = sP + 392;
    float* t1 = sQ + 392;
    float* t2 = t1 + 64;
    float* rsuminv = t2 + 64;
    if (t < 64) { t1[t] = th1[t]; t2[t] = th2[t]; }
    for (int i = t; i < 392; i += 256) {
      const int j = i / 49, m = i - j * 49;
      sS[j * 49 + m] = Sbuf[(((size_t)b * NHD + j) * 49 + n) * 49 + m];
    }
    __syncthreads();
    for (int i = t; i < 392; i += 256) {
      const int j = i / 49, m = i - j * 49;
      float a = 0.f;
#pragma unroll
      for (int jj = 0; jj < 8; ++jj) a += t1[j * 8 + jj] * sS[jj * 49 + m];
      sP[j * 49 + m] = a;
    }
    __syncthreads();
    if (t < 8) {
      float mx = -1e30f;
      for (int m = 0; m < 49; ++m) mx = fmaxf(mx, sP[t * 49 + m]);
      float s = 0.f;
      for (int m = 0; m < 49; ++m) { float e = expf(sP[t * 49 + m] - mx); sP[t * 49 + m] = e; s += e; }
      rsuminv[t] = 1.f / s;
    }
    __syncthreads();
    for (int i = t; i < 392; i += 256) {
      const int j = i / 49, m = i - j * 49;
      float a = 0.f;
#pragma unroll
      for (int jj = 0; jj < 8; ++jj) a += t2[j * 8 + jj] * (sP[jj * 49 + m] * rsuminv[jj]);
      sQ[j * 49 + m] = a;
    }
    __syncthreads();
    for (int c = t; c < NC; c += 256) {
      const int hh = c >> 6;
      const float* vp = vb + ((size_t)b * NC + c) * 49;
      float a = 0.f;
      for (int m = 0; m < 49; ++m) a += sQ[hh * 49 + m] * vp[m];
      y7[((size_t)b * 49 + n) * NC + c] = a;
    }
  } else {
    const int i2 = bid - 1568;
    const int n0 = (i2 % 13) * 128;
    const int g = i2 / 13;
    __hip_bfloat16* lsA = (__hip_bfloat16*)smem;
    __hip_bfloat16* lsB = lsA + 4096;
    const int lane = t & 63, wid = t >> 6;
    const int wm = (wid >> 1) * 32, wn = (wid & 1) * 64;
    const int fr = lane & 15, fq = lane >> 4;
    const int rslot = (fq ^ ((fr >> 1) & 3)) * 8;
    const int srow = t >> 2;
    const int scol = ((t & 3) ^ ((t >> 3) & 3)) * 8;
    const __hip_bfloat16* Ab = lwb  + ((size_t)g * 64 + srow) * KLOC + scol;
    const __hip_bfloat16* Bb = bloc + ((size_t)g * NTOKP + n0 + srow) * KLOC + scol;

    const f32x4 fz = {0.f, 0.f, 0.f, 0.f};
    f32x4 acc[2][4];
#pragma unroll
    for (int i = 0; i < 2; ++i)
#pragma unroll
      for (int j = 0; j < 4; ++j) acc[i][j] = fz;

#define STG_VL(tile)                                                      \
  do {                                                                    \
    const int kof = (tile) * 32; const int bb = (tile) & 1;               \
    gload_lds16(Ab + kof,                      lsA + bb * 2048 + wid * 512); \
    gload_lds16(Bb + kof,                      lsB + bb * 4096 + wid * 512); \
    gload_lds16(Bb + kof + (size_t)64 * KLOC,  lsB + bb * 4096 + 2048 + wid * 512); \
  } while (0)

    STG_VL(0);
    STG_VL(1);
#pragma unroll 1
    for (int it = 0; it < 18; ++it) {
      if (it < 17) asm volatile("s_waitcnt vmcnt(3)" ::: "memory");
      else         asm volatile("s_waitcnt vmcnt(0)" ::: "memory");
      __builtin_amdgcn_sched_barrier(0);
      __builtin_amdgcn_s_barrier();
      __builtin_amdgcn_sched_barrier(0);
      const __hip_bfloat16* lA = lsA + (it & 1) * 2048;
      const __hip_bfloat16* lB = lsB + (it & 1) * 4096;
      short8 af[2], bf[4];
#pragma unroll
      for (int mi = 0; mi < 2; ++mi)
        af[mi] = *(const short8*)(lA + (wm + mi * 16 + fr) * 32 + rslot);
#pragma unroll
      for (int ni = 0; ni < 4; ++ni)
        bf[ni] = *(const short8*)(lB + (wn + ni * 16 + fr) * 32 + rslot);
#pragma unroll
      for (int mi = 0; mi < 2; ++mi)
#pragma unroll
        for (int ni = 0; ni < 4; ++ni)
          acc[mi][ni] = __builtin_amdgcn_mfma_f32_16x16x32_bf16(af[mi], bf[ni], acc[mi][ni], 0, 0, 0);
      __builtin_amdgcn_sched_barrier(0);
      __builtin_amdgcn_s_barrier();
      __builtin_amdgcn_sched_barrier(0);
      if (it < 16) STG_VL(it + 2);
    }
#undef STG_VL

#pragma unroll
    for (int mi = 0; mi < 2; ++mi) {
#pragma unroll
      for (int ni = 0; ni < 4; ++ni) {
        const int gn = n0 + wn + ni * 16 + fr;
        if (gn >= NTOK) continue;
        const int b = gn / 49, n = gn - b * 49;
#pragma unroll
        for (int r = 0; r < 4; ++r) {
          const int oc = g * 64 + wm + mi * 16 + fq * 4 + r;
          const float sc = sl[oc];
          vloc[((size_t)b * 49 + n) * NC + oc] = acc[mi][ni][r] * sc + lbias[oc] * sc + bl[oc];
        }
      }
    }
  }
}

// ---------------------------------------------------------------- bilinear 7->56 of (y7 + vloc) + hardswish -> h[100352][512] bf16
// NT stores: h_buf is a 100 MB stream consumed later via L3; keep L2 for
// the y7/vloc read set (8x bilinear row reuse).
__global__ __launch_bounds__(256) void k_resize(const float* __restrict__ y7,
                                                const float* __restrict__ vloc,
                                                __hip_bfloat16* __restrict__ h) {
  const int y = blockIdx.x, b = blockIdx.y, t = threadIdx.x;
  __shared__ float L[2][7][512];
  float sy = (y - 3.5f) * 0.125f;
  sy = fminf(fmaxf(sy, 0.f), 6.f);
  const int iy0 = min((int)floorf(sy), 5);
  const float wy = sy - (float)iy0;
  const size_t rowoff = ((size_t)b * 49 + iy0 * 7) * NC;
  const float* src  = y7 + rowoff;
  const float* vsrc = vloc + rowoff;
  float* Lf = &L[0][0][0];
  for (int i = t; i < 2 * 7 * 512; i += 256) Lf[i] = src[i] + vsrc[i];
  __syncthreads();
  const size_t outb = ((size_t)b * P56 + (size_t)y * 56) * NC;
  const int cg = (t & 63) * 8;
  const int xq = t >> 6;
  for (int x0 = 0; x0 < 56; x0 += 4) {
    const int x = x0 + xq;
    float sx = (x - 3.5f) * 0.125f;
    sx = fminf(fmaxf(sx, 0.f), 6.f);
    const int ix0 = min((int)floorf(sx), 5);
    const float wx = sx - (float)ix0;
    const float w00 = (1.f - wy) * (1.f - wx), w01 = (1.f - wy) * wx;
    const float w10 = wy * (1.f - wx),         w11 = wy * wx;
    short8 pk;
#pragma unroll
    for (int j = 0; j < 8; ++j) {
      const int c = cg + j;
      const float v = w00 * L[0][ix0][c] + w01 * L[0][ix0 + 1][c]
                    + w10 * L[1][ix0][c] + w11 * L[1][ix0 + 1][c];
      const float hs = v * fminf(fmaxf(v + 3.f, 0.f), 6.f) * (1.f / 6.f);
      pk[j] = (short)__bfloat16_as_ushort(__float2bfloat16(hs));
    }
    __builtin_nontemporal_store(pk, (short8*)(&h[outb + (size_t)x * NC + cg]));
  }
}

// ----------------------------------------------------------------
extern "C" void kernel_launch(void* const* d_in, const int* in_sizes, int n_in,
                              void* d_out, int out_size, void* d_ws, size_t ws_size,
                              hipStream_t stream) {
  (void)in_sizes; (void)n_in; (void)out_size; (void)ws_size;
  const float* x     = (const float*)d_in[0];
  const float* dw_w  = (const float*)d_in[1];
  const float* bn0_s = (const float*)d_in[2];
  const float* bn0_b = (const float*)d_in[3];
  const float* wq    = (const float*)d_in[4];
  const float* bnq_s = (const float*)d_in[5];
  const float* bnq_b = (const float*)d_in[6];
  const float* wk    = (const float*)d_in[7];
  const float* bnk_s = (const float*)d_in[8];
  const float* bnk_b = (const float*)d_in[9];
  const float* wv    = (const float*)d_in[10];
  const float* bnv_s = (const float*)d_in[11];
  const float* bnv_b = (const float*)d_in[12];
  const float* loc_w = (const float*)d_in[13];
  const float* loc_b = (const float*)d_in[14];
  const float* bnl_s = (const float*)d_in[15];
  const float* bnl_b = (const float*)d_in[16];
  const float* th1   = (const float*)d_in[17];
  const float* th2   = (const float*)d_in[18];
  const float* lsc   = (const float*)d_in[19];
  const float* ab    = (const float*)d_in[20];
  const float* wo    = (const float*)d_in[21];
  const float* bno_s = (const float*)d_in[22];
  const float* bno_b = (const float*)d_in[23];
  const int*   bidx  = (const int*)d_in[24];

  char* w = (char*)d_ws;
  auto alloc = [&](size_t bytes) {
    char* p = w;
    w += (bytes + 255) & ~(size_t)255;
    return p;
  };
  __hip_bfloat16* h_buf = (__hip_bfloat16*)alloc((size_t)NBIG * NC * 2);
  __hip_bfloat16* wq_b  = (__hip_bfloat16*)alloc((size_t)NC * NC * 2);
  __hip_bfloat16* wk_b  = (__hip_bfloat16*)alloc((size_t)NC * NC * 2);
  __hip_bfloat16* wv_b  = (__hip_bfloat16*)alloc((size_t)NC * NC * 2);
  __hip_bfloat16* wo_b  = (__hip_bfloat16*)alloc((size_t)NC * NC * 2);
  __hip_bfloat16* lw_b  = (__hip_bfloat16*)alloc((size_t)NC * KLOC * 2);
  __hip_bfloat16* xs    = (__hip_bfloat16*)alloc((size_t)NTOKP * NC * 2);
  float* qb   = (float*)alloc((size_t)NB * NC * 49 * 4);
  float* kb   = (float*)alloc((size_t)NB * NC * 49 * 4);
  float* vb   = (float*)alloc((size_t)NB * NC * 49 * 4);
  float* vloc = (float*)alloc((size_t)NB * 49 * NC * 4);   // [b][n][c] layout
  float* y7   = (float*)alloc((size_t)NB * 49 * NC * 4);
  float* Sb   = (float*)alloc((size_t)NB * NHD * 49 * 49 * 4);
  __hip_bfloat16* bloc = (__hip_bfloat16*)h_buf;   // aliased; dies before h_buf written

  k_stride_cvt<<<dim3(4096 + 656), 256, 0, stream>>>(
      x, dw_w, bn0_s, bn0_b, xs,
      wq, wk, wv, wo, loc_w, wq_b, wk_b, wv_b, wo_b, lw_b);
  k_gemm_qkv<<<dim3(13 * 12), 256, 0, stream>>>(wq_b, wk_b, wv_b, xs,
                                                bnq_s, bnq_b, bnk_s, bnk_b, bnv_s, bnv_b,
                                                qb, kb, vb);
  k_mid1<<<dim3(512), 256, 0, stream>>>(qb, kb, lsc, ab, bidx, Sb, vb, bloc);
  k_mid2<<<dim3(1568 + 104), 256, 0, stream>>>(Sb, th1, th2, vb, y7,
                                               lw_b, bloc, loc_b, bnl_s, bnl_b, vloc);
  k_resize<<<dim3(RES, NB), 256, 0, stream>>>(y7, vloc, h_buf);
  k_gemm_big<<<dim3(784), 512, 0, stream>>>(wo_b, h_buf, bno_s, bno_b, (float*)d_out);
}

// Round 20
// 221.772 us; speedup vs baseline: 1.0361x; 1.0361x over previous
//
#include <hip/hip_runtime.h>
#include <hip/hip_bf16.h>
#include <stdint.h>

typedef short short8 __attribute__((ext_vector_type(8)));
typedef float f32x4 __attribute__((ext_vector_type(4)));

#define NB    32
#define NC    512
#define NHD   8
#define HDD   64
#define N7    49
#define RES   56
#define P56   3136
#define NTOK  1568     // 32*49
#define NTOKP 1664     // padded to 13*128 for unguarded staging
#define NBIG  100352   // 32*3136
#define KDIM  512
#define KLOC  576      // 64ci * 9taps

// async global->LDS, 16B per lane; LDS dest is wave-uniform base + lane*16
__device__ __forceinline__ void gload_lds16(const __hip_bfloat16* g, __hip_bfloat16* l) {
  __builtin_amdgcn_global_load_lds(
      (const __attribute__((address_space(1))) void*)g,
      (__attribute__((address_space(3))) void*)l, 16, 0, 0);
}

// ---------------------------------------------------------------- fused: depthwise 3x3 stride-8 + BN0 (blocks 0..4095)
//                                                                   + fp32->bf16 weight convert (blocks 4096..4751)
__global__ __launch_bounds__(256) void k_stride_cvt(
    const float* __restrict__ x, const float* __restrict__ dw,
    const float* __restrict__ s0, const float* __restrict__ b0,
    __hip_bfloat16* __restrict__ xs,
    const float* __restrict__ c0, const float* __restrict__ c1,
    const float* __restrict__ c2, const float* __restrict__ c3,
    const float* __restrict__ c4,
    __hip_bfloat16* __restrict__ d0, __hip_bfloat16* __restrict__ d1,
    __hip_bfloat16* __restrict__ d2, __hip_bfloat16* __restrict__ d3,
    __hip_bfloat16* __restrict__ d4) {
  const int bid = blockIdx.x, t = threadIdx.x;
  if (bid >= 4096) {
    const long base = (long)(bid - 4096) * 2048;
#pragma unroll
    for (int j = 0; j < 8; ++j) {
      long i = base + t + j * 256;
      const float* s; __hip_bfloat16* d; long off;
      if (i >= 1048576)      { s = c4; d = d4; off = i - 1048576; }
      else if (i >= 786432)  { s = c3; d = d3; off = i - 786432; }
      else if (i >= 524288)  { s = c2; d = d2; off = i - 524288; }
      else if (i >= 262144)  { s = c1; d = d1; off = i - 262144; }
      else                   { s = c0; d = d0; off = i; }
      d[off] = __float2bfloat16(s[off]);
    }
    return;
  }
  const int b = bid >> 7, cig = bid & 127;
  const int sub = t >> 6, lane = t & 63;
  const int ci = cig * 4 + sub;
  __shared__ float rows[4][21][56];
  const float* xp = x + ((size_t)(b * NC + ci)) * RES * RES;
  for (int r = lane; r < 21 * 56; r += 64) {
    int rr = r / 56, cc = r - rr * 56;
    int oh = rr / 3, kh = rr - oh * 3;
    int ih = oh * 8 + kh - 1;
    rows[sub][rr][cc] = (ih >= 0) ? xp[ih * 56 + cc] : 0.f;
  }
  float w[9];
#pragma unroll
  for (int j = 0; j < 9; ++j) w[j] = dw[ci * 9 + j];
  const float sc = s0[ci], bi = b0[ci];
  __syncthreads();
  if (lane < 49) {
    const int oh = lane / 7, ow = lane - oh * 7;
    float acc = 0.f;
#pragma unroll
    for (int kh = 0; kh < 3; ++kh)
#pragma unroll
      for (int kw = 0; kw < 3; ++kw) {
        int col = ow * 8 + kw - 1;
        float v = (col >= 0) ? rows[sub][oh * 3 + kh][col] : 0.f;
        acc += v * w[kh * 3 + kw];
      }
    xs[(size_t)(b * 49 + lane) * NC + ci] = __float2bfloat16(acc * sc + bi);
  }
}

// ---------------------------------------------------------------- BIG GEMM: 256x256, BK=32, ring-2, 2 resident blocks/CU,
// counted vmcnt(4), verified conflict-free swizzle, LDS-transpose epilogue
// with NON-TEMPORAL dwordx4 stores (d_out never re-read; confirmed -17us R17).
__global__ __launch_bounds__(512) void k_gemm_big(
    const __hip_bfloat16* __restrict__ A,    // [512][512] bf16
    const __hip_bfloat16* __restrict__ Bm,   // [100352][512] bf16
    const float* __restrict__ scale, const float* __restrict__ bias,
    float* __restrict__ out) {
  __shared__ __align__(16) __hip_bfloat16 lsA[2][256 * 32];   // 32 KB
  __shared__ __align__(16) __hip_bfloat16 lsB[2][256 * 32];   // 32 KB
  const int t = threadIdx.x;
  const int cpx = gridDim.x >> 3;
  const int nid = (blockIdx.x & 7) * cpx + (blockIdx.x >> 3);
  const int m0 = (nid & 1) * 256, n0 = (nid >> 1) * 256;

  const int lane = t & 63, wid = t >> 6;
  const int wm = (wid >> 2) * 128, wn = (wid & 3) * 64;   // 2M x 4N waves
  const int fr = lane & 15, fq = lane >> 4;
  const int rslot = (fq ^ ((fr >> 1) & 3)) * 8;           // verified conflict-free

  const int srow = t >> 2;                                 // 0..127
  const int scol = ((t & 3) ^ ((t >> 3) & 3)) * 8;         // stage-side inverse
  const __hip_bfloat16* Ab = A  + (size_t)(m0 + srow) * KDIM + scol;
  const __hip_bfloat16* Bb = Bm + (size_t)(n0 + srow) * KDIM + scol;

  const f32x4 fz = {0.f, 0.f, 0.f, 0.f};
  f32x4 acc[8][4];
#pragma unroll
  for (int i = 0; i < 8; ++i)
#pragma unroll
    for (int j = 0; j < 4; ++j) acc[i][j] = fz;

#define STA(tile, call) gload_lds16(Ab + (tile) * 32 + (size_t)(call) * 128 * KDIM, \
                                    lsA[(tile) & 1] + (call) * 4096 + wid * 512)
#define STB(tile, call) gload_lds16(Bb + (tile) * 32 + (size_t)(call) * 128 * KDIM, \
                                    lsB[(tile) & 1] + (call) * 4096 + wid * 512)

  STA(0, 0); STA(0, 1); STB(0, 0); STB(0, 1);
  STA(1, 0); STA(1, 1); STB(1, 0); STB(1, 1);

#pragma unroll 1
  for (int tt = 0; tt < 16; ++tt) {
    if (tt < 15) asm volatile("s_waitcnt vmcnt(4)" ::: "memory");
    else         asm volatile("s_waitcnt vmcnt(0)" ::: "memory");
    __builtin_amdgcn_sched_barrier(0);
    __builtin_amdgcn_s_barrier();          // buf[tt&1] = tile tt, visible to all
    __builtin_amdgcn_sched_barrier(0);

    const __hip_bfloat16* lA = lsA[tt & 1];
    const __hip_bfloat16* lB = lsB[tt & 1];
    short8 af[4], ag[4], bf[4];
#pragma unroll
    for (int i = 0; i < 4; ++i)
      af[i] = *(const short8*)(lA + (wm + i * 16 + fr) * 32 + rslot);
#pragma unroll
    for (int i = 0; i < 4; ++i)
      ag[i] = *(const short8*)(lA + (wm + 64 + i * 16 + fr) * 32 + rslot);
#pragma unroll
    for (int j = 0; j < 4; ++j)
      bf[j] = *(const short8*)(lB + (wn + j * 16 + fr) * 32 + rslot);
    __builtin_amdgcn_s_setprio(1);
#pragma unroll
    for (int i = 0; i < 4; ++i)
#pragma unroll
      for (int j = 0; j < 4; ++j)
        acc[i][j] = __builtin_amdgcn_mfma_f32_16x16x32_bf16(af[i], bf[j], acc[i][j], 0, 0, 0);
#pragma unroll
    for (int i = 0; i < 4; ++i)
#pragma unroll
      for (int j = 0; j < 4; ++j)
        acc[4 + i][j] = __builtin_amdgcn_mfma_f32_16x16x32_bf16(ag[i], bf[j], acc[4 + i][j], 0, 0, 0);
    __builtin_amdgcn_s_setprio(0);

    __builtin_amdgcn_sched_barrier(0);
    __builtin_amdgcn_s_barrier();          // all reads of buf[tt&1] complete
    __builtin_amdgcn_sched_barrier(0);
    if (tt < 14) { STA(tt + 2, 0); STA(tt + 2, 1); STB(tt + 2, 0); STB(tt + 2, 1); }
  }
#undef STA
#undef STB

  // ---- LDS-transpose epilogue, non-temporal dwordx4 stores.
  float* scr = (float*)&lsA[0][0] + (size_t)wid * 1100;   // 16*68=1088 used
  const int gnb = n0 + wn;                 // multiple of 64; never crosses P56
  const int outer = gnb / P56;
  const int iib = gnb - outer * P56;
  const int erow = lane >> 4;              // 0..3
  const int ecol = (lane & 15) * 4;        // 0..60
#pragma unroll
  for (int mi = 0; mi < 8; ++mi) {
    const int cob = m0 + wm + mi * 16;
#pragma unroll
    for (int ni = 0; ni < 4; ++ni) {
#pragma unroll
      for (int r = 0; r < 4; ++r) {
        const int co = cob + fq * 4 + r;
        scr[(fq * 4 + r) * 68 + ni * 16 + fr] = acc[mi][ni][r] * scale[co] + bias[co];
      }
    }
#pragma unroll
    for (int p = 0; p < 4; ++p) {
      const int row = p * 4 + erow;        // 0..15
      f32x4 v = *(const f32x4*)(scr + row * 68 + ecol);
      __builtin_nontemporal_store(
          v, (f32x4*)(&out[((size_t)outer * NC + cob + row) * P56 + iib + ecol]));
    }
  }
}

// ---------------------------------------------------------------- fused QKV GEMM (ring-2, unchanged)
__global__ __launch_bounds__(256) void k_gemm_qkv(
    const __hip_bfloat16* __restrict__ wqb, const __hip_bfloat16* __restrict__ wkb,
    const __hip_bfloat16* __restrict__ wvb, const __hip_bfloat16* __restrict__ xs,
    const float* __restrict__ sq, const float* __restrict__ bq,
    const float* __restrict__ sk, const float* __restrict__ bk,
    const float* __restrict__ sv, const float* __restrict__ bv,
    float* __restrict__ qb, float* __restrict__ kb, float* __restrict__ vb) {
  __shared__ __align__(16) __hip_bfloat16 lsA[2][128 * 32];
  __shared__ __align__(16) __hip_bfloat16 lsB[2][128 * 32];
  const int t = threadIdx.x;
  const int nwg = gridDim.x;
  const int orig = blockIdx.x;
  const int q = nwg >> 3, r = nwg & 7;
  const int xcd = orig & 7, pos = orig >> 3;
  const int nid = (xcd < r ? xcd * (q + 1) : r * (q + 1) + (xcd - r) * q) + pos;
  const int mt = nid % 12, nt = nid / 12;
  const int n0 = nt * 128, m0 = (mt & 3) * 128, sel = mt >> 2;

  const __hip_bfloat16* A = (sel == 0 ? wqb : sel == 1 ? wkb : wvb);
  const float* scale = (sel == 0 ? sq : sel == 1 ? sk : sv);
  const float* bias  = (sel == 0 ? bq : sel == 1 ? bk : bv);
  float* out = (sel == 0 ? qb : sel == 1 ? kb : vb);

  const int lane = t & 63, wid = t >> 6;
  const int wm = (wid >> 1) * 64, wn = (wid & 1) * 64;
  const int fr = lane & 15, fq = lane >> 4;
  const int rslot = (fq ^ ((fr >> 1) & 3)) * 8;
  const int srow = t >> 2;
  const int scol = ((t & 3) ^ ((t >> 3) & 3)) * 8;
  const __hip_bfloat16* Ab = A  + (size_t)(m0 + srow) * KDIM + scol;
  const __hip_bfloat16* Bb = xs + (size_t)(n0 + srow) * KDIM + scol;

  const f32x4 fz = {0.f, 0.f, 0.f, 0.f};
  f32x4 acc[4][4];
#pragma unroll
  for (int i = 0; i < 4; ++i)
#pragma unroll
    for (int j = 0; j < 4; ++j) acc[i][j] = fz;

#define STG_QKV(tile)                                                   \
  do {                                                                  \
    const int kof = (tile) * 32; const int bb = (tile) & 1;             \
    gload_lds16(Ab + kof,                       lsA[bb] + wid * 512);   \
    gload_lds16(Ab + kof + (size_t)64 * KDIM,   lsA[bb] + 2048 + wid * 512); \
    gload_lds16(Bb + kof,                       lsB[bb] + wid * 512);   \
    gload_lds16(Bb + kof + (size_t)64 * KDIM,   lsB[bb] + 2048 + wid * 512); \
  } while (0)

  STG_QKV(0);
  STG_QKV(1);
#pragma unroll 1
  for (int it = 0; it < 16; ++it) {
    if (it < 15) asm volatile("s_waitcnt vmcnt(4)" ::: "memory");
    else         asm volatile("s_waitcnt vmcnt(0)" ::: "memory");
    __builtin_amdgcn_sched_barrier(0);
    __builtin_amdgcn_s_barrier();
    __builtin_amdgcn_sched_barrier(0);
    const __hip_bfloat16* lA = lsA[it & 1];
    const __hip_bfloat16* lB = lsB[it & 1];
    short8 af[4], bf[4];
#pragma unroll
    for (int mi = 0; mi < 4; ++mi)
      af[mi] = *(const short8*)(lA + (wm + mi * 16 + fr) * 32 + rslot);
#pragma unroll
    for (int ni = 0; ni < 4; ++ni)
      bf[ni] = *(const short8*)(lB + (wn + ni * 16 + fr) * 32 + rslot);
#pragma unroll
    for (int mi = 0; mi < 4; ++mi)
#pragma unroll
      for (int ni = 0; ni < 4; ++ni)
        acc[mi][ni] = __builtin_amdgcn_mfma_f32_16x16x32_bf16(af[mi], bf[ni], acc[mi][ni], 0, 0, 0);
    __builtin_amdgcn_sched_barrier(0);
    __builtin_amdgcn_s_barrier();
    __builtin_amdgcn_sched_barrier(0);
    if (it < 14) STG_QKV(it + 2);
  }
#undef STG_QKV

#pragma unroll
  for (int mi = 0; mi < 4; ++mi) {
#pragma unroll
    for (int ni = 0; ni < 4; ++ni) {
      const int gn = n0 + wn + ni * 16 + fr;
      if (gn >= NTOK) continue;
      const int b = gn / 49, ii = gn - b * 49;
#pragma unroll
      for (int r = 0; r < 4; ++r) {
        const int co = m0 + wm + mi * 16 + fq * 4 + r;
        out[((size_t)b * NC + co) * 49 + ii] = acc[mi][ni][r] * scale[co] + bias[co];
      }
    }
  }
}

// ---------------------------------------------------------------- MID1: attn1 (blocks 0..255) || im2col (blocks 256..511)
__global__ __launch_bounds__(256) void k_mid1(
    const float* __restrict__ qb, const float* __restrict__ kb,
    const float* __restrict__ lsc, const float* __restrict__ ab, const int* __restrict__ bidx,
    float* __restrict__ Sbuf,
    const float* __restrict__ vb, __hip_bfloat16* __restrict__ bloc) {
  __shared__ __align__(16) char smem[25792];
  const int bid = blockIdx.x, t = threadIdx.x;
  if (bid < 256) {
    const int h = bid & 7, b = bid >> 3;
    float* qt  = (float*)smem;
    float* kt  = qt + 3136;
    float* nq  = kt + 3136;
    float* abl = nq + 49;
    const float* qs = qb + ((size_t)b * NC + h * 64) * 49;
    const float* ks = kb + ((size_t)b * NC + h * 64) * 49;
    for (int i = t; i < 64 * 49; i += 256) { qt[i] = qs[i]; kt[i] = ks[i]; }
    if (t < 49) abl[t] = ab[h * 49 + t];
    __syncthreads();
    if (t < 49) {
      float s = 0.f;
      for (int d = 0; d < 64; ++d) { float v = qt[d * 49 + t]; s += v * v; }
      nq[t] = fmaxf(sqrtf(s), 1e-12f);
    } else if (t >= 64 && t < 128) {
      const int d = t - 64;
      float s = 0.f;
      for (int m = 0; m < 49; ++m) { float v = kt[d * 49 + m]; s += v * v; }
      const float inv = 1.f / fmaxf(sqrtf(s), 1e-12f);
      for (int m = 0; m < 49; ++m) kt[d * 49 + m] *= inv;
    }
    __syncthreads();
    const float ls = expf(fminf(lsc[h], logf(100.f)));
    for (int idx = t; idx < 49 * 49; idx += 256) {
      const int n = idx / 49, m = idx - n * 49;
      float acc = 0.f;
      for (int d = 0; d < 64; ++d) acc += qt[d * 49 + n] * kt[d * 49 + m];
      Sbuf[(((size_t)b * NHD + h) * 49 + n) * 49 + m] = acc / nq[n] * ls + abl[bidx[idx]];
    }
  } else {
    const int i2 = bid - 256;
    const int g = i2 & 7, b = i2 >> 3;
    __hip_bfloat16* pad = (__hip_bfloat16*)smem;   // [64][81]
    for (int i = t; i < 64 * 81; i += 256) pad[i] = __float2bfloat16(0.f);
    __syncthreads();
    const float* src = vb + ((size_t)b * NC + g * 64) * 49;
    for (int i = t; i < 64 * 49; i += 256) {
      const int ci = i / 49, n = i - ci * 49;
      const int oh = n / 7, ow = n - oh * 7;
      pad[ci * 81 + (oh + 1) * 9 + (ow + 1)] = __float2bfloat16(src[i]);
    }
    __syncthreads();
    __hip_bfloat16* dst = bloc + ((size_t)g * NTOKP + (size_t)b * 49) * KLOC;
    for (int i8 = t; i8 < 49 * KLOC / 8; i8 += 256) {
      const int i = i8 * 8;
      const int n = i / KLOC, k0 = i - n * KLOC;
      const int oh = n / 7, ow = n - oh * 7;
      short8 pk;
#pragma unroll
      for (int j = 0; j < 8; ++j) {
        const int k = k0 + j;
        const int ci = k / 9, tap = k - ci * 9;
        const int kh = tap / 3, kw = tap - kh * 3;
        pk[j] = (short)__bfloat16_as_ushort(pad[ci * 81 + (oh + kh) * 9 + (ow + kw)]);
      }
      *(short8*)(dst + (size_t)n * KLOC + k0) = pk;
    }
  }
}

// ---------------------------------------------------------------- MID2: attn2-noVloc (blocks 0..1567) || vloc GEMM (1568..1671)
__global__ __launch_bounds__(256) void k_mid2(
    const float* __restrict__ Sbuf, const float* __restrict__ th1, const float* __restrict__ th2,
    const float* __restrict__ vb, float* __restrict__ y7,
    const __hip_bfloat16* __restrict__ lwb, const __hip_bfloat16* __restrict__ bloc,
    const float* __restrict__ lbias, const float* __restrict__ sl,
    const float* __restrict__ bl, float* __restrict__ vloc) {
  __shared__ __align__(16) char smem[24576];
  const int bid = blockIdx.x, t = threadIdx.x;
  if (bid < 1568) {
    const int n = bid % 49, b = bid / 49;
    float* sS = (float*)smem;
    float* sP = sS + 392;
    float* sQ = sP + 392;
    float* t1 = sQ + 392;
    float* t2 = t1 + 64;
    float* rsuminv = t2 + 64;
    if (t < 64) { t1[t] = th1[t]; t2[t] = th2[t]; }
    for (int i = t; i < 392; i += 256) {
      const int j = i / 49, m = i - j * 49;
      sS[j * 49 + m] = Sbuf[(((size_t)b * NHD + j) * 49 + n) * 49 + m];
    }
    __syncthreads();
    for (int i = t; i < 392; i += 256) {
      const int j = i / 49, m = i - j * 49;
      float a = 0.f;
#pragma unroll
      for (int jj = 0; jj < 8; ++jj) a += t1[j * 8 + jj] * sS[jj * 49 + m];
      sP[j * 49 + m] = a;
    }
    __syncthreads();
    if (t < 8) {
      float mx = -1e30f;
      for (int m = 0; m < 49; ++m) mx = fmaxf(mx, sP[t * 49 + m]);
      float s = 0.f;
      for (int m = 0; m < 49; ++m) { float e = expf(sP[t * 49 + m] - mx); sP[t * 49 + m] = e; s += e; }
      rsuminv[t] = 1.f / s;
    }
    __syncthreads();
    for (int i = t; i < 392; i += 256) {
      const int j = i / 49, m = i - j * 49;
      float a = 0.f;
#pragma unroll
      for (int jj = 0; jj < 8; ++jj) a += t2[j * 8 + jj] * (sP[jj * 49 + m] * rsuminv[jj]);
      sQ[j * 49 + m] = a;
    }
    __syncthreads();
    for (int c = t; c < NC; c += 256) {
      const int hh = c >> 6;
      const float* vp = vb + ((size_t)b * NC + c) * 49;
      float a = 0.f;
      for (int m = 0; m < 49; ++m) a += sQ[hh * 49 + m] * vp[m];
      y7[((size_t)b * 49 + n) * NC + c] = a;
    }
  } else {
    const int i2 = bid - 1568;
    const int n0 = (i2 % 13) * 128;
    const int g = i2 / 13;
    __hip_bfloat16* lsA = (__hip_bfloat16*)smem;
    __hip_bfloat16* lsB = lsA + 4096;
    const int lane = t & 63, wid = t >> 6;
    const int wm = (wid >> 1) * 32, wn = (wid & 1) * 64;
    const int fr = lane & 15, fq = lane >> 4;
    const int rslot = (fq ^ ((fr >> 1) & 3)) * 8;
    const int srow = t >> 2;
    const int scol = ((t & 3) ^ ((t >> 3) & 3)) * 8;
    const __hip_bfloat16* Ab = lwb  + ((size_t)g * 64 + srow) * KLOC + scol;
    const __hip_bfloat16* Bb = bloc + ((size_t)g * NTOKP + n0 + srow) * KLOC + scol;

    const f32x4 fz = {0.f, 0.f, 0.f, 0.f};
    f32x4 acc[2][4];
#pragma unroll
    for (int i = 0; i < 2; ++i)
#pragma unroll
      for (int j = 0; j < 4; ++j) acc[i][j] = fz;

#define STG_VL(tile)                                                      \
  do {                                                                    \
    const int kof = (tile) * 32; const int bb = (tile) & 1;               \
    gload_lds16(Ab + kof,                      lsA + bb * 2048 + wid * 512); \
    gload_lds16(Bb + kof,                      lsB + bb * 4096 + wid * 512); \
    gload_lds16(Bb + kof + (size_t)64 * KLOC,  lsB + bb * 4096 + 2048 + wid * 512); \
  } while (0)

    STG_VL(0);
    STG_VL(1);
#pragma unroll 1
    for (int it = 0; it < 18; ++it) {
      if (it < 17) asm volatile("s_waitcnt vmcnt(3)" ::: "memory");
      else         asm volatile("s_waitcnt vmcnt(0)" ::: "memory");
      __builtin_amdgcn_sched_barrier(0);
      __builtin_amdgcn_s_barrier();
      __builtin_amdgcn_sched_barrier(0);
      const __hip_bfloat16* lA = lsA + (it & 1) * 2048;
      const __hip_bfloat16* lB = lsB + (it & 1) * 4096;
      short8 af[2], bf[4];
#pragma unroll
      for (int mi = 0; mi < 2; ++mi)
        af[mi] = *(const short8*)(lA + (wm + mi * 16 + fr) * 32 + rslot);
#pragma unroll
      for (int ni = 0; ni < 4; ++ni)
        bf[ni] = *(const short8*)(lB + (wn + ni * 16 + fr) * 32 + rslot);
#pragma unroll
      for (int mi = 0; mi < 2; ++mi)
#pragma unroll
        for (int ni = 0; ni < 4; ++ni)
          acc[mi][ni] = __builtin_amdgcn_mfma_f32_16x16x32_bf16(af[mi], bf[ni], acc[mi][ni], 0, 0, 0);
      __builtin_amdgcn_sched_barrier(0);
      __builtin_amdgcn_s_barrier();
      __builtin_amdgcn_sched_barrier(0);
      if (it < 16) STG_VL(it + 2);
    }
#undef STG_VL

#pragma unroll
    for (int mi = 0; mi < 2; ++mi) {
#pragma unroll
      for (int ni = 0; ni < 4; ++ni) {
        const int gn = n0 + wn + ni * 16 + fr;
        if (gn >= NTOK) continue;
        const int b = gn / 49, n = gn - b * 49;
#pragma unroll
        for (int r = 0; r < 4; ++r) {
          const int oc = g * 64 + wm + mi * 16 + fq * 4 + r;
          const float sc = sl[oc];
          vloc[((size_t)b * 49 + n) * NC + oc] = acc[mi][ni][r] * sc + lbias[oc] * sc + bl[oc];
        }
      }
    }
  }
}

// ---------------------------------------------------------------- bilinear 7->56 of (y7 + vloc) + hardswish -> h[100352][512] bf16
// NORMAL stores (h_buf IS re-read by the big GEMM; NT here regressed, R18).
__global__ __launch_bounds__(256) void k_resize(const float* __restrict__ y7,
                                                const float* __restrict__ vloc,
                                                __hip_bfloat16* __restrict__ h) {
  const int y = blockIdx.x, b = blockIdx.y, t = threadIdx.x;
  __shared__ float L[2][7][512];
  float sy = (y - 3.5f) * 0.125f;
  sy = fminf(fmaxf(sy, 0.f), 6.f);
  const int iy0 = min((int)floorf(sy), 5);
  const float wy = sy - (float)iy0;
  const size_t rowoff = ((size_t)b * 49 + iy0 * 7) * NC;
  const float* src  = y7 + rowoff;
  const float* vsrc = vloc + rowoff;
  float* Lf = &L[0][0][0];
  for (int i = t; i < 2 * 7 * 512; i += 256) Lf[i] = src[i] + vsrc[i];
  __syncthreads();
  const size_t outb = ((size_t)b * P56 + (size_t)y * 56) * NC;
  const int cg = (t & 63) * 8;
  const int xq = t >> 6;
  for (int x0 = 0; x0 < 56; x0 += 4) {
    const int x = x0 + xq;
    float sx = (x - 3.5f) * 0.125f;
    sx = fminf(fmaxf(sx, 0.f), 6.f);
    const int ix0 = min((int)floorf(sx), 5);
    const float wx = sx - (float)ix0;
    const float w00 = (1.f - wy) * (1.f - wx), w01 = (1.f - wy) * wx;
    const float w10 = wy * (1.f - wx),         w11 = wy * wx;
    short8 pk;
#pragma unroll
    for (int j = 0; j < 8; ++j) {
      const int c = cg + j;
      const float v = w00 * L[0][ix0][c] + w01 * L[0][ix0 + 1][c]
                    + w10 * L[1][ix0][c] + w11 * L[1][ix0 + 1][c];
      const float hs = v * fminf(fmaxf(v + 3.f, 0.f), 6.f) * (1.f / 6.f);
      pk[j] = (short)__bfloat16_as_ushort(__float2bfloat16(hs));
    }
    *(short8*)(&h[outb + (size_t)x * NC + cg]) = pk;
  }
}

// ----------------------------------------------------------------
extern "C" void kernel_launch(void* const* d_in, const int* in_sizes, int n_in,
                              void* d_out, int out_size, void* d_ws, size_t ws_size,
                              hipStream_t stream) {
  (void)in_sizes; (void)n_in; (void)out_size; (void)ws_size;
  const float* x     = (const float*)d_in[0];
  const float* dw_w  = (const float*)d_in[1];
  const float* bn0_s = (const float*)d_in[2];
  const float* bn0_b = (const float*)d_in[3];
  const float* wq    = (const float*)d_in[4];
  const float* bnq_s = (const float*)d_in[5];
  const float* bnq_b = (const float*)d_in[6];
  const float* wk    = (const float*)d_in[7];
  const float* bnk_s = (const float*)d_in[8];
  const float* bnk_b = (const float*)d_in[9];
  const float* wv    = (const float*)d_in[10];
  const float* bnv_s = (const float*)d_in[11];
  const float* bnv_b = (const float*)d_in[12];
  const float* loc_w = (const float*)d_in[13];
  const float* loc_b = (const float*)d_in[14];
  const float* bnl_s = (const float*)d_in[15];
  const float* bnl_b = (const float*)d_in[16];
  const float* th1   = (const float*)d_in[17];
  const float* th2   = (const float*)d_in[18];
  const float* lsc   = (const float*)d_in[19];
  const float* ab    = (const float*)d_in[20];
  const float* wo    = (const float*)d_in[21];
  const float* bno_s = (const float*)d_in[22];
  const float* bno_b = (const float*)d_in[23];
  const int*   bidx  = (const int*)d_in[24];

  char* w = (char*)d_ws;
  auto alloc = [&](size_t bytes) {
    char* p = w;
    w += (bytes + 255) & ~(size_t)255;
    return p;
  };
  __hip_bfloat16* h_buf = (__hip_bfloat16*)alloc((size_t)NBIG * NC * 2);
  __hip_bfloat16* wq_b  = (__hip_bfloat16*)alloc((size_t)NC * NC * 2);
  __hip_bfloat16* wk_b  = (__hip_bfloat16*)alloc((size_t)NC * NC * 2);
  __hip_bfloat16* wv_b  = (__hip_bfloat16*)alloc((size_t)NC * NC * 2);
  __hip_bfloat16* wo_b  = (__hip_bfloat16*)alloc((size_t)NC * NC * 2);
  __hip_bfloat16* lw_b  = (__hip_bfloat16*)alloc((size_t)NC * KLOC * 2);
  __hip_bfloat16* xs    = (__hip_bfloat16*)alloc((size_t)NTOKP * NC * 2);
  float* qb   = (float*)alloc((size_t)NB * NC * 49 * 4);
  float* kb   = (float*)alloc((size_t)NB * NC * 49 * 4);
  float* vb   = (float*)alloc((size_t)NB * NC * 49 * 4);
  float* vloc = (float*)alloc((size_t)NB * 49 * NC * 4);   // [b][n][c] layout
  float* y7   = (float*)alloc((size_t)NB * 49 * NC * 4);
  float* Sb   = (float*)alloc((size_t)NB * NHD * 49 * 49 * 4);
  __hip_bfloat16* bloc = (__hip_bfloat16*)h_buf;   // aliased; dies before h_buf written

  k_stride_cvt<<<dim3(4096 + 656), 256, 0, stream>>>(
      x, dw_w, bn0_s, bn0_b, xs,
      wq, wk, wv, wo, loc_w, wq_b, wk_b, wv_b, wo_b, lw_b);
  k_gemm_qkv<<<dim3(13 * 12), 256, 0, stream>>>(wq_b, wk_b, wv_b, xs,
                                                bnq_s, bnq_b, bnk_s, bnk_b, bnv_s, bnv_b,
                                                qb, kb, vb);
  k_mid1<<<dim3(512), 256, 0, stream>>>(qb, kb, lsc, ab, bidx, Sb, vb, bloc);
  k_mid2<<<dim3(1568 + 104), 256, 0, stream>>>(Sb, th1, th2, vb, y7,
                                               lw_b, bloc, loc_b, bnl_s, bnl_b, vloc);
  k_resize<<<dim3(RES, NB), 256, 0, stream>>>(y7, vloc, h_buf);
  k_gemm_big<<<dim3(784), 512, 0, stream>>>(wo_b, h_buf, bno_s, bno_b, (float*)d_out);
}